// Round 5
// baseline (773.121 us; speedup 1.0000x reference)
//
#include <hip/hip_runtime.h>
#include <cstdint>
#include <cstddef>

#define BN_INV 0.9999950000374997f  /* 1/sqrt(1+1e-5) */
#define REP 8  /* diagnostic repetition: idempotent re-execution to surface
                  per-kernel counters in rocprof top-5. Remove next round. */

typedef __attribute__((ext_vector_type(8))) _Float16 h8v;
typedef __attribute__((ext_vector_type(4))) float f4v;

// split v = hi + lo, both fp16; residual <= 2^-22 * |v|
__device__ __forceinline__ void fsplit(float v, ushort& h, ushort& l) {
    _Float16 hh = (_Float16)v;
    _Float16 ll = (_Float16)(v - (float)hh);
    h = __builtin_bit_cast(ushort, hh);
    l = __builtin_bit_cast(ushort, ll);
}

// ---------------------------------------------------------------------------
// Repack helper: (O,I,3,3) fp32 -> split fp16 hi/lo planes, A-frag order.
// ---------------------------------------------------------------------------
__device__ __forceinline__ void repack_one(
    const float* __restrict__ w, ushort* __restrict__ dst, int CIN, int i)
{
    int ocf = i / (CIN * 9);
    int r = i % (CIN * 9);
    int ic = r / 9;
    int tap = r % 9;
    int ocg = ocf >> 6, oc = ocf & 63;
    int chunk = ic >> 5, q = (ic >> 3) & 3, j = ic & 7;
    int nch = CIN >> 5;
    ushort h, l;
    fsplit(w[i], h, l);
    size_t base = (size_t)((ocg * nch + chunk) * 2) * 18432
                + (size_t)tap * 2048 + q * 512 + oc * 8 + j;
    dst[base] = h;
    dst[base + 18432] = l;
}

// ---------------------------------------------------------------------------
// Fused prep + conv1 (round-3 structure; conv1 path wrapped in REP loop).
// ---------------------------------------------------------------------------
__global__ __launch_bounds__(256) void prep_conv1_kernel(
    const float* __restrict__ w0, const float* __restrict__ w1,
    float* __restrict__ U,
    const float* __restrict__ w2, ushort* __restrict__ wb2,
    const float* __restrict__ w3, ushort* __restrict__ wb3,
    const float* __restrict__ w4, ushort* __restrict__ wb4,
    const float* __restrict__ x, const float* __restrict__ wt,
    const float* __restrict__ g, const float* __restrict__ be,
    float* __restrict__ out, ushort* __restrict__ pooled)
{
    __shared__ float s_in[4][132];

    int blk = blockIdx.x;
    int tid = threadIdx.x;

    if (blk >= 2048) {
        if (blk >= 2424)     { repack_one(w4, wb4, 128, (blk - 2424) * 256 + tid); return; }
        if (blk >= 2136)     { repack_one(w3, wb3,  64, (blk - 2136) * 256 + tid); return; }
        if (blk >= 2064)     { repack_one(w2, wb2,  32, (blk - 2064) * 256 + tid); return; }

        int idx = (blk - 2048) * 256 + tid;  // = c*16 + r
        int c = idx >> 4, r = idx & 15;
        float gr[4][2][2], gi[4][2][2];
        const float inv_sq2 = 0.70710678118654752f;
#pragma unroll
        for (int w = 0; w < 4; ++w) {
            float ty = w0[c * 2 + (w & 1)];
            float tz = w1[c * 2 + (w & 1)];
            float cy = cosf(0.5f * ty), sy = sinf(0.5f * ty);
            float cz = cosf(0.5f * tz), sz = sinf(0.5f * tz);
            float r00 = (cy - sy) * inv_sq2, r01 = (cy + sy) * inv_sq2;
            float r10 = (cy + sy) * inv_sq2, r11 = (sy - cy) * inv_sq2;
            gr[w][0][0] = cz * r00; gi[w][0][0] = -sz * r00;
            gr[w][0][1] = cz * r01; gi[w][0][1] = -sz * r01;
            gr[w][1][0] = cz * r10; gi[w][1][0] =  sz * r10;
            gr[w][1][1] = cz * r11; gi[w][1][1] =  sz * r11;
        }
        const int PTOT[16] = {0,13,3,14,6,11,5,8,12,1,15,2,10,7,9,4};
        int rp = PTOT[r];
        float* Uo = U + (size_t)c * 512 + r * 32;
#pragma unroll
        for (int cc = 0; cc < 16; ++cc) {
            float pr = 1.f, pi = 0.f;
#pragma unroll
            for (int w = 0; w < 4; ++w) {
                int ib = (rp >> (3 - w)) & 1, jb = (cc >> (3 - w)) & 1;
                float ar = gr[w][ib][jb], ai = gi[w][ib][jb];
                float nr = pr * ar - pi * ai;
                float ni = pr * ai + pi * ar;
                pr = nr; pi = ni;
            }
            Uo[cc * 2 + 0] = pr;
            Uo[cc * 2 + 1] = pi;
        }
        return;
    }

    // ---- conv1 path: tile 128 wide x 2 tall ----
    int b = blk >> 8;
    int rest = blk & 255;
    int ty0 = (rest >> 1) * 2;
    int tx0 = (rest & 1) * 128;

    int xx = ((tid >> 2) << 1) | (tid & 1);   // 0..127
    int yy = (tid >> 1) & 1;                  // 0..1
    bool wr_pool = (tid & 3) == 0;
    ushort* op = pooled + (((size_t)b * 128 + (ty0 >> 1)) * 128 + (tx0 >> 1) + (tid >> 2)) * 64;
    size_t obase = ((size_t)b * 32) * 65536 + (size_t)(ty0 + yy) * 256 + (tx0 + xx);

#pragma unroll 1
    for (int rep = 0; rep < REP; ++rep) {
        __syncthreads();   // protect s_in reuse across reps
        for (int i = tid; i < 520; i += 256) {
            int yyi = i / 130, xxi = i % 130;
            int gy = ty0 + yyi - 1, gx = tx0 + xxi - 1;
            float v = 0.f;
            if (gy >= 0 && gy < 256 && gx >= 0 && gx < 256)
                v = x[(size_t)b * 65536 + gy * 256 + gx];
            s_in[yyi][xxi] = v;
        }
        __syncthreads();

        float t[3][3];
#pragma unroll
        for (int i = 0; i < 3; ++i)
#pragma unroll
            for (int j = 0; j < 3; ++j) t[i][j] = s_in[yy + i][xx + j];

#pragma unroll
        for (int k = 0; k < 4; ++k) {
            uint4 uh, ul;
#pragma unroll
            for (int j = 0; j < 8; ++j) {
                const int oc = k * 8 + j;
                float s = wt[oc*9+0] * t[0][0] + wt[oc*9+1] * t[0][1] + wt[oc*9+2] * t[0][2]
                        + wt[oc*9+3] * t[1][0] + wt[oc*9+4] * t[1][1] + wt[oc*9+5] * t[1][2]
                        + wt[oc*9+6] * t[2][0] + wt[oc*9+7] * t[2][1] + wt[oc*9+8] * t[2][2];
                s = s * (g[oc] * BN_INV) + be[oc];
                s = fmaxf(s, 0.f);
                out[obase + (size_t)oc * 65536] = s;
                float p = fmaxf(s, __shfl_xor(s, 1));   // x-pair (tid bit0)
                p = fmaxf(p, __shfl_xor(p, 2));         // y-pair (tid bit1)
                ushort h, l;
                fsplit(p, h, l);
                uint hw = (uint)h, lw = (uint)l;
                if (j == 0) { uh.x = hw; ul.x = lw; }
                else if (j == 1) { uh.x |= hw << 16; ul.x |= lw << 16; }
                else if (j == 2) { uh.y = hw; ul.y = lw; }
                else if (j == 3) { uh.y |= hw << 16; ul.y |= lw << 16; }
                else if (j == 4) { uh.z = hw; ul.z = lw; }
                else if (j == 5) { uh.z |= hw << 16; ul.z |= lw << 16; }
                else if (j == 6) { uh.w = hw; ul.w = lw; }
                else             { uh.w |= hw << 16; ul.w |= lw << 16; }
            }
            if (wr_pool) {
                *(uint4*)(op + 8 * k) = uh;
                *(uint4*)(op + 32 + 8 * k) = ul;
            }
        }
    }
}

// ---------------------------------------------------------------------------
// Split-fp16 MFMA implicit-GEMM 3x3 conv + BN + ReLU, optional fused pool.
// Round-2 structure, body wrapped in REP loop (idempotent).
// ---------------------------------------------------------------------------
template <int CIN, int COUT, int HW, bool POOL>
__global__ __launch_bounds__(512) void conv3x3_mfma_split(
    const ushort* __restrict__ in,   // (8,HW,HW,2*CIN)
    const ushort* __restrict__ wb,   // packed split
    const float* __restrict__ g, const float* __restrict__ be,
    float* __restrict__ out,         // (8,COUT,HW,HW) fp32
    ushort* __restrict__ pooled)     // (8,HW/2,HW/2,2*COUT) if POOL
{
    constexpr int NCH = CIN / 32;
    constexpr int NTX = HW / 16;
    constexpr int NT = NTX * (HW / 8);
    constexpr int NOCG = COUT / 64;
    constexpr int PS = 72;
    constexpr int BUFSZ = 180 * PS;          // 12960 ushorts = 25920 B
    constexpr int NBUF = (NCH > 1) ? 2 : 1;

    __shared__ __align__(16) ushort s_in[NBUF * BUFSZ];

    constexpr int NWG = NT * NOCG * 8;
    int bid = blockIdx.x;
    bid = (bid & 7) * (NWG >> 3) + (bid >> 3);   // XCD-bijective swizzle

    int tile = bid % NT;
    int rest = bid / NT;
    int ocg = rest % NOCG;
    int b = rest / NOCG;
    int x0 = (tile % NTX) * 16;
    int y0 = (tile / NTX) * 8;

    int tid = threadIdx.x;
    int wv = tid >> 6;           // 0..7
    int lane = tid & 63;
    int n = lane & 15;
    int q = lane >> 4;
    int oc_half = (wv & 1) * 32;
    int sg = wv >> 1;            // site-group: rows sg*2, sg*2+1

    int ib[2];
#pragma unroll
    for (int f = 0; f < 2; ++f)
        ib[f] = ((sg * 2 + f) * 18 + n) * PS + q * 8;
    int iwa0 = q * 512 + (oc_half + n) * 8;
    int iwa1 = q * 512 + (oc_half + 16 + n) * 8;

    const ushort* inb = in + (size_t)b * HW * HW * 2 * CIN;

    auto stage = [&](int ch, int bsel) {
#pragma unroll
        for (int it = 0; it < 6; ++it) {
            int i = tid + it * 512;
            if (i < 2880) {
                int pos = i >> 4;
                int r2 = i & 15;
                int comp = r2 >> 3;
                int u = r2 & 7;
                int py = pos / 18, px = pos % 18;
                int gy = y0 - 1 + py, gx = x0 - 1 + px;
                uint2 v; v.x = 0u; v.y = 0u;
                if (gy >= 0 && gy < HW && gx >= 0 && gx < HW)
                    v = *(const uint2*)(inb + ((size_t)gy * HW + gx) * (2 * CIN)
                                        + comp * CIN + ch * 32 + u * 4);
                *(uint2*)(&s_in[bsel * BUFSZ + pos * PS + comp * 32 + u * 4]) = v;
            }
        }
    };

#pragma unroll 1
    for (int rep = 0; rep < REP; ++rep) {
        __syncthreads();   // prev rep's LDS reads done before restage

        f4v acc[2][2];
#pragma unroll
        for (int a = 0; a < 2; ++a)
#pragma unroll
            for (int f = 0; f < 2; ++f) acc[a][f] = (f4v){0.f, 0.f, 0.f, 0.f};

        stage(0, 0);
        int cur = 0;
        for (int ch = 0; ch < NCH; ++ch) {
            __syncthreads();                       // buf[cur] ready
            if (ch + 1 < NCH) stage(ch + 1, cur ^ 1);

            const ushort* wc = wb + (size_t)((ocg * NCH + ch) * 2) * 18432;
            const ushort* sb = &s_in[cur * BUFSZ];
            __builtin_amdgcn_s_setprio(1);
#pragma unroll 3
            for (int tap = 0; tap < 9; ++tap) {
                const int toff = ((tap / 3) * 18 + (tap % 3)) * PS;
                const ushort* wt_ = wc + tap * 2048;
                h8v ah0 = *(const h8v*)(wt_ + iwa0);
                h8v ah1 = *(const h8v*)(wt_ + iwa1);
                h8v al0 = *(const h8v*)(wt_ + 18432 + iwa0);
                h8v al1 = *(const h8v*)(wt_ + 18432 + iwa1);
                h8v bh[2], bl[2];
#pragma unroll
                for (int f = 0; f < 2; ++f) {
                    bh[f] = *(const h8v*)(&sb[toff + ib[f]]);
                    bl[f] = *(const h8v*)(&sb[toff + ib[f] + 32]);
                }
#pragma unroll
                for (int f = 0; f < 2; ++f) {
                    acc[0][f] = __builtin_amdgcn_mfma_f32_16x16x32_f16(ah0, bh[f], acc[0][f], 0, 0, 0);
                    acc[1][f] = __builtin_amdgcn_mfma_f32_16x16x32_f16(ah1, bh[f], acc[1][f], 0, 0, 0);
                }
#pragma unroll
                for (int f = 0; f < 2; ++f) {
                    acc[0][f] = __builtin_amdgcn_mfma_f32_16x16x32_f16(ah0, bl[f], acc[0][f], 0, 0, 0);
                    acc[1][f] = __builtin_amdgcn_mfma_f32_16x16x32_f16(ah1, bl[f], acc[1][f], 0, 0, 0);
                }
#pragma unroll
                for (int f = 0; f < 2; ++f) {
                    acc[0][f] = __builtin_amdgcn_mfma_f32_16x16x32_f16(al0, bh[f], acc[0][f], 0, 0, 0);
                    acc[1][f] = __builtin_amdgcn_mfma_f32_16x16x32_f16(al1, bh[f], acc[1][f], 0, 0, 0);
                }
            }
            __builtin_amdgcn_s_setprio(0);
            cur ^= (NBUF - 1);
        }

        // epilogue
        float vr[2][2][4];
#pragma unroll
        for (int tf = 0; tf < 2; ++tf)
#pragma unroll
            for (int f = 0; f < 2; ++f) {
                int y = y0 + sg * 2 + f;
#pragma unroll
                for (int r = 0; r < 4; ++r) {
                    int oc = ocg * 64 + oc_half + tf * 16 + q * 4 + r;
                    float v = fmaxf(acc[tf][f][r] * (g[oc] * BN_INV) + be[oc], 0.f);
                    vr[tf][f][r] = v;
                    out[((size_t)(b * COUT + oc) * HW + y) * HW + (x0 + n)] = v;
                }
            }

        if (POOL) {
#pragma unroll
            for (int tf = 0; tf < 2; ++tf) {
                ushort h[4], l[4];
#pragma unroll
                for (int r = 0; r < 4; ++r) {
                    float p = fmaxf(vr[tf][0][r], vr[tf][1][r]);
                    p = fmaxf(p, __shfl_xor(p, 1));
                    fsplit(p, h[r], l[r]);
                }
                if ((n & 1) == 0) {
                    int pyp = (y0 >> 1) + sg;
                    int pxp = (x0 + n) >> 1;
                    int ocb = ocg * 64 + oc_half + tf * 16 + q * 4;
                    ushort* op = pooled
                        + (((size_t)b * (HW / 2) + pyp) * (HW / 2) + pxp) * (2 * COUT);
                    uint2 uh, ul;
                    uh.x = (uint)h[0] | ((uint)h[1] << 16);
                    uh.y = (uint)h[2] | ((uint)h[3] << 16);
                    ul.x = (uint)l[0] | ((uint)l[1] << 16);
                    ul.y = (uint)l[2] | ((uint)l[3] << 16);
                    *(uint2*)(op + ocb) = uh;
                    *(uint2*)(op + COUT + ocb) = ul;
                }
            }
        }
    }
}

// ---------------------------------------------------------------------------
// Quantum stage + BN + ReLU (round-3 structure, REP loop; pre-transform
// input kept in registers so in-place repetition is idempotent).
// ---------------------------------------------------------------------------
__global__ __launch_bounds__(256) void quantum_bn_relu(
    const float* __restrict__ e4,  // (8,256,32,32)
    const float* __restrict__ U,   // (256,16,16,2)
    const float* __restrict__ g5, const float* __restrict__ b5,
    float* __restrict__ out)       // (8,256,32,32)
{
    int blk = blockIdx.x;      // b*256 + c
    int c = blk & 255;
    __shared__ float sp[35][36];
    __shared__ __align__(16) float sU[512];

    int tid = threadIdx.x;
    for (int i = tid; i < 35 * 36; i += 256) ((float*)sp)[i] = 0.f;
    const float4* Usrc = (const float4*)(U + (size_t)c * 512);
    if (tid < 128) ((float4*)sU)[tid] = Usrc[tid];
    float4 pv = ((const float4*)(e4 + (size_t)blk * 1024))[tid];  // pre-transform
    __syncthreads();

    int y = tid >> 3, x4 = (tid & 7) << 2;
    float sc = g5[c] * BN_INV, bi = b5[c];

#pragma unroll 1
    for (int rep = 0; rep < REP; ++rep) {
        asm volatile("" : "+v"(pv.x), "+v"(pv.y), "+v"(pv.z), "+v"(pv.w));
        sp[y + 1][x4 + 1] = pv.x;
        sp[y + 1][x4 + 2] = pv.y;
        sp[y + 1][x4 + 3] = pv.z;
        sp[y + 1][x4 + 4] = pv.w;
        __syncthreads();

        float rows[4][8];
#pragma unroll
        for (int i = 0; i < 4; ++i) {
            float4 a = *(const float4*)&sp[y + i][x4];
            float4 bq = *(const float4*)&sp[y + i][x4 + 4];
            rows[i][0] = a.x;  rows[i][1] = a.y;  rows[i][2] = a.z;  rows[i][3] = a.w;
            rows[i][4] = bq.x; rows[i][5] = bq.y; rows[i][6] = bq.z; rows[i][7] = bq.w;
        }

        float inv2[4];
#pragma unroll
        for (int k = 0; k < 4; ++k) {
            float ss = 0.f;
#pragma unroll
            for (int i = 0; i < 4; ++i)
#pragma unroll
                for (int j = 0; j < 4; ++j) {
                    float v = rows[i][k + j];
                    ss += v * v;
                }
            float inv = 1.f / fmaxf(sqrtf(ss), 1e-12f);
            inv2[k] = inv * inv;
        }

        const int   RI[10] = {0, 1, 2, 4, 7, 8, 11, 13, 14, 15};
        const float ZM[10] = {1.f, .5f, .5f, .5f, -.5f, .5f, -.5f, -.5f, -.5f, -1.f};
        const float4* sU4 = (const float4*)sU;

        float s[4] = {0.f, 0.f, 0.f, 0.f};
#pragma unroll
        for (int ii = 0; ii < 10; ++ii) {
            int i = RI[ii];
            float re0 = 0.f, im0 = 0.f, re1 = 0.f, im1 = 0.f;
            float re2 = 0.f, im2 = 0.f, re3 = 0.f, im3 = 0.f;
#pragma unroll
            for (int jj = 0; jj < 8; ++jj) {
                float4 uu = sU4[i * 8 + jj];
                const int e0 = 2 * jj, e1 = 2 * jj + 1;
                float a0 = rows[e0 >> 2][0 + (e0 & 3)];
                float a1 = rows[e0 >> 2][1 + (e0 & 3)];
                float a2 = rows[e0 >> 2][2 + (e0 & 3)];
                float a3 = rows[e0 >> 2][3 + (e0 & 3)];
                re0 += uu.x * a0; im0 += uu.y * a0;
                re1 += uu.x * a1; im1 += uu.y * a1;
                re2 += uu.x * a2; im2 += uu.y * a2;
                re3 += uu.x * a3; im3 += uu.y * a3;
                float c0 = rows[e1 >> 2][0 + (e1 & 3)];
                float c1 = rows[e1 >> 2][1 + (e1 & 3)];
                float c2 = rows[e1 >> 2][2 + (e1 & 3)];
                float c3 = rows[e1 >> 2][3 + (e1 & 3)];
                re0 += uu.z * c0; im0 += uu.w * c0;
                re1 += uu.z * c1; im1 += uu.w * c1;
                re2 += uu.z * c2; im2 += uu.w * c2;
                re3 += uu.z * c3; im3 += uu.w * c3;
            }
            float zm = ZM[ii];
            s[0] += (re0 * re0 + im0 * im0) * zm;
            s[1] += (re1 * re1 + im1 * im1) * zm;
            s[2] += (re2 * re2 + im2 * im2) * zm;
            s[3] += (re3 * re3 + im3 * im3) * zm;
        }

        float4 o;
        o.x = fmaxf(((s[0] * inv2[0] + 1.f) * 0.5f) * sc + bi, 0.f);
        o.y = fmaxf(((s[1] * inv2[1] + 1.f) * 0.5f) * sc + bi, 0.f);
        o.z = fmaxf(((s[2] * inv2[2] + 1.f) * 0.5f) * sc + bi, 0.f);
        o.w = fmaxf(((s[3] * inv2[3] + 1.f) * 0.5f) * sc + bi, 0.f);
        *(float4*)(out + (size_t)blk * 1024 + y * 32 + x4) = o;
        __syncthreads();   // sp reads done before next rep rewrites
    }
}

// ---------------------------------------------------------------------------
extern "C" void kernel_launch(void* const* d_in, const int* in_sizes, int n_in,
                              void* d_out, int out_size, void* d_ws, size_t ws_size,
                              hipStream_t stream)
{
    const float* x   = (const float*)d_in[0];
    const float* w1  = (const float*)d_in[1];
    const float* g1  = (const float*)d_in[2];
    const float* b1  = (const float*)d_in[3];
    const float* w2  = (const float*)d_in[4];
    const float* g2  = (const float*)d_in[5];
    const float* b2  = (const float*)d_in[6];
    const float* w3  = (const float*)d_in[7];
    const float* g3  = (const float*)d_in[8];
    const float* b3  = (const float*)d_in[9];
    const float* w4  = (const float*)d_in[10];
    const float* g4  = (const float*)d_in[11];
    const float* b4  = (const float*)d_in[12];
    const float* qw0 = (const float*)d_in[13];
    const float* qw1 = (const float*)d_in[14];
    const float* g5  = (const float*)d_in[15];
    const float* b5  = (const float*)d_in[16];

    float* out = (float*)d_out;
    float* e1  = out;                         // 8*32*256*256 = 16777216
    float* e2  = out + 16777216;              // 8*64*128*128 =  8388608
    float* e3  = out + 25165824;              // 8*128*64*64  =  4194304
    float* o4  = out + 29360128;              // 8*256*32*32  =  2097152

    float* ws = (float*)d_ws;
    float*  Uw  = ws;
    ushort* wb2 = (ushort*)(ws + 131072);
    ushort* wb3 = (ushort*)(ws + 149504);
    ushort* wb4 = (ushort*)(ws + 223232);
    ushort* pt1 = (ushort*)(ws + 518144);     // (8,128,128,64)
    ushort* pt2 = (ushort*)(ws + 4712448);    // (8,64,64,128)
    ushort* pt3 = (ushort*)(ws + 518144);     // (8,32,32,256), aliases pt1

    prep_conv1_kernel<<<2048 + 1528, 256, 0, stream>>>(
        qw0, qw1, Uw, w2, wb2, w3, wb3, w4, wb4,
        x, w1, g1, b1, e1, pt1);

    conv3x3_mfma_split<32, 64, 128, true><<<1024, 512, 0, stream>>>(pt1, wb2, g2, b2, e2, pt2);

    conv3x3_mfma_split<64, 128, 64, true><<<512, 512, 0, stream>>>(pt2, wb3, g3, b3, e3, pt3);

    conv3x3_mfma_split<128, 256, 32, false><<<256, 512, 0, stream>>>(pt3, wb4, g4, b4, o4, nullptr);

    quantum_bn_relu<<<2048, 256, 0, stream>>>(o4, Uw, g5, b5, o4);
}

// Round 7
// 242.700 us; speedup vs baseline: 3.1855x; 3.1855x over previous
//
#include <hip/hip_runtime.h>
#include <cstdint>
#include <cstddef>

#define BN_INV 0.9999950000374997f  /* 1/sqrt(1+1e-5) */

typedef __attribute__((ext_vector_type(8))) _Float16 h8v;
typedef __attribute__((ext_vector_type(4))) float f4v;
typedef __attribute__((ext_vector_type(2))) float f2v;

// split v = hi + lo, both fp16; residual <= 2^-22 * |v|
__device__ __forceinline__ void fsplit(float v, ushort& h, ushort& l) {
    _Float16 hh = (_Float16)v;
    _Float16 ll = (_Float16)(v - (float)hh);
    h = __builtin_bit_cast(ushort, hh);
    l = __builtin_bit_cast(ushort, ll);
}

// ---------------------------------------------------------------------------
// Repack helper: (O,I,3,3) fp32 -> split fp16 hi/lo planes, A-frag order.
// ---------------------------------------------------------------------------
__device__ __forceinline__ void repack_one(
    const float* __restrict__ w, ushort* __restrict__ dst, int CIN, int i)
{
    int ocf = i / (CIN * 9);
    int r = i % (CIN * 9);
    int ic = r / 9;
    int tap = r % 9;
    int ocg = ocf >> 6, oc = ocf & 63;
    int chunk = ic >> 5, q = (ic >> 3) & 3, j = ic & 7;
    int nch = CIN >> 5;
    ushort h, l;
    fsplit(w[i], h, l);
    size_t base = (size_t)((ocg * nch + chunk) * 2) * 18432
                + (size_t)tap * 2048 + q * 512 + oc * 8 + j;
    dst[base] = h;
    dst[base + 18432] = l;
}

// ---------------------------------------------------------------------------
// Fused prep + conv1.
// Blocks 0..1023: conv1, tile 128 wide x 4 tall, 2 x-adjacent sites/thread.
//   float2 packed math (v_pk_fma_f32), float2 e1 stores (256-B runs/wave),
//   cvt_pkrtz paired fp16 split for the pooled pt1 output.
// Blocks 1024..1039: build U. 1040..2551: repack w2/w3/w4.
// ---------------------------------------------------------------------------
__global__ __launch_bounds__(256) void prep_conv1_kernel(
    const float* __restrict__ w0, const float* __restrict__ w1,
    float* __restrict__ U,
    const float* __restrict__ w2, ushort* __restrict__ wb2,
    const float* __restrict__ w3, ushort* __restrict__ wb3,
    const float* __restrict__ w4, ushort* __restrict__ wb4,
    const float* __restrict__ x, const float* __restrict__ wt,
    const float* __restrict__ g, const float* __restrict__ be,
    float* __restrict__ out, ushort* __restrict__ pooled)
{
    __shared__ float s_in[6][132];  // rows ty0-1..ty0+4, cols tx0-1..tx0+128

    int blk = blockIdx.x;
    int tid = threadIdx.x;

    if (blk >= 1024) {
        if (blk >= 1400)     { repack_one(w4, wb4, 128, (blk - 1400) * 256 + tid); return; }
        if (blk >= 1112)     { repack_one(w3, wb3,  64, (blk - 1112) * 256 + tid); return; }
        if (blk >= 1040)     { repack_one(w2, wb2,  32, (blk - 1040) * 256 + tid); return; }

        int idx = (blk - 1024) * 256 + tid;  // = c*16 + r
        int c = idx >> 4, r = idx & 15;
        float gr[4][2][2], gi[4][2][2];
        const float inv_sq2 = 0.70710678118654752f;
#pragma unroll
        for (int w = 0; w < 4; ++w) {
            float ty = w0[c * 2 + (w & 1)];
            float tz = w1[c * 2 + (w & 1)];
            float cy = cosf(0.5f * ty), sy = sinf(0.5f * ty);
            float cz = cosf(0.5f * tz), sz = sinf(0.5f * tz);
            float r00 = (cy - sy) * inv_sq2, r01 = (cy + sy) * inv_sq2;
            float r10 = (cy + sy) * inv_sq2, r11 = (sy - cy) * inv_sq2;
            gr[w][0][0] = cz * r00; gi[w][0][0] = -sz * r00;
            gr[w][0][1] = cz * r01; gi[w][0][1] = -sz * r01;
            gr[w][1][0] = cz * r10; gi[w][1][0] =  sz * r10;
            gr[w][1][1] = cz * r11; gi[w][1][1] =  sz * r11;
        }
        const int PTOT[16] = {0,13,3,14,6,11,5,8,12,1,15,2,10,7,9,4};
        int rp = PTOT[r];
        float* Uo = U + (size_t)c * 512 + r * 32;
#pragma unroll
        for (int cc = 0; cc < 16; ++cc) {
            float pr = 1.f, pi = 0.f;
#pragma unroll
            for (int w = 0; w < 4; ++w) {
                int ib = (rp >> (3 - w)) & 1, jb = (cc >> (3 - w)) & 1;
                float ar = gr[w][ib][jb], ai = gi[w][ib][jb];
                float nr = pr * ar - pi * ai;
                float ni = pr * ai + pi * ar;
                pr = nr; pi = ni;
            }
            Uo[cc * 2 + 0] = pr;
            Uo[cc * 2 + 1] = pi;
        }
        return;
    }

    // ---- conv1 path: tile 128 wide x 4 tall; thread = (y, x-pair) ----
    int b = blk >> 7;                 // 128 tiles/image
    int rest = blk & 127;
    int ty0 = (rest >> 1) * 4;
    int tx0 = (rest & 1) * 128;

    for (int i = tid; i < 780; i += 256) {   // 6 rows x 130 cols
        int yy = i / 130, xx = i % 130;
        int gy = ty0 + yy - 1, gx = tx0 + xx - 1;
        float v = 0.f;
        if (gy >= 0 && gy < 256 && gx >= 0 && gx < 256)
            v = x[(size_t)b * 65536 + gy * 256 + gx];
        s_in[yy][xx] = v;
    }
    __syncthreads();

    int w = tid >> 6;                 // wave 0..3
    int lane = tid & 63;
    int xp = (w & 1) * 32 + (lane >> 1);   // x-pair index 0..63
    int ylo = lane & 1;
    int y = (w >> 1) * 2 + ylo;            // row 0..3
    int x0s = xp * 2;                      // even site 0..126

    // t2[i][j] = {in[y+i][x0s-1+j], in[y+i][x0s+j]} (global), staged col = x0s+j
    f2v t2[3][3];
#pragma unroll
    for (int i = 0; i < 3; ++i) {
        f2v a = *(const f2v*)&s_in[y + i][x0s];
        f2v bq = *(const f2v*)&s_in[y + i][x0s + 2];
        t2[i][0] = a;
        t2[i][1] = (f2v){a.y, bq.x};
        t2[i][2] = bq;
    }

    bool wr_pool = (ylo == 0);
    int pyp = (ty0 >> 1) + (w >> 1);
    int pxp = (tx0 >> 1) + xp;
    ushort* op = pooled + (((size_t)b * 128 + pyp) * 128 + pxp) * 64;
    size_t obase = ((size_t)b * 32) * 65536 + (size_t)(ty0 + y) * 256 + (tx0 + x0s);

#pragma unroll
    for (int k = 0; k < 4; ++k) {
        uint uhw[4], ulw[4];
#pragma unroll
        for (int j2 = 0; j2 < 4; ++j2) {
            const int oc0 = k * 8 + j2 * 2;
            const int oc1 = oc0 + 1;
            f2v s0 = {0.f, 0.f}, s1 = {0.f, 0.f};
#pragma unroll
            for (int i = 0; i < 3; ++i)
#pragma unroll
                for (int j = 0; j < 3; ++j) {
                    s0 += wt[oc0 * 9 + i * 3 + j] * t2[i][j];
                    s1 += wt[oc1 * 9 + i * 3 + j] * t2[i][j];
                }
            float gs0 = g[oc0] * BN_INV, be0 = be[oc0];
            float gs1 = g[oc1] * BN_INV, be1 = be[oc1];
            s0 = s0 * gs0 + (f2v){be0, be0};
            s1 = s1 * gs1 + (f2v){be1, be1};
            s0.x = fmaxf(s0.x, 0.f); s0.y = fmaxf(s0.y, 0.f);
            s1.x = fmaxf(s1.x, 0.f); s1.y = fmaxf(s1.y, 0.f);
            *(f2v*)(out + obase + (size_t)oc0 * 65536) = s0;
            *(f2v*)(out + obase + (size_t)oc1 * 65536) = s1;
            // 2x2 pool: x-pair intra-thread, y-pair via lane^1
            float p0 = fmaxf(s0.x, s0.y);
            float p1 = fmaxf(s1.x, s1.y);
            p0 = fmaxf(p0, __shfl_xor(p0, 1));
            p1 = fmaxf(p1, __shfl_xor(p1, 1));
            auto hh = __builtin_amdgcn_cvt_pkrtz(p0, p1);   // __fp16 x2
            uhw[j2] = __builtin_bit_cast(uint, hh);
            float l0 = p0 - (float)hh.x;
            float l1 = p1 - (float)hh.y;
            auto ll = __builtin_amdgcn_cvt_pkrtz(l0, l1);
            ulw[j2] = __builtin_bit_cast(uint, ll);
        }
        if (wr_pool) {
            uint4 uh = {uhw[0], uhw[1], uhw[2], uhw[3]};
            uint4 ul = {ulw[0], ulw[1], ulw[2], ulw[3]};
            *(uint4*)(op + 8 * k) = uh;
            *(uint4*)(op + 32 + 8 * k) = ul;
        }
    }
}

// ---------------------------------------------------------------------------
// Split-fp16 MFMA implicit-GEMM 3x3 conv + BN + ReLU, optional fused pool.
// NCH>1: double-buffered chunk loop (unchanged, verified).
// NCH==1 (conv2): split-stage + T14 overlap — stage pos<144 (rows 0..7),
// issue rows 8..9 loads to regs, compute taps 0..2 (reads pos<144 only:
// max pos = 7*18+15+2 = 143), ds_write the regs, barrier, taps 3..8.
// ---------------------------------------------------------------------------
template <int CIN, int COUT, int HW, bool POOL>
__global__ __launch_bounds__(512) void conv3x3_mfma_split(
    const ushort* __restrict__ in,   // (8,HW,HW,2*CIN)
    const ushort* __restrict__ wb,   // packed split
    const float* __restrict__ g, const float* __restrict__ be,
    float* __restrict__ out,         // (8,COUT,HW,HW) fp32
    ushort* __restrict__ pooled)     // (8,HW/2,HW/2,2*COUT) if POOL
{
    constexpr int NCH = CIN / 32;
    constexpr int NTX = HW / 16;
    constexpr int NT = NTX * (HW / 8);
    constexpr int NOCG = COUT / 64;
    constexpr int PS = 72;
    constexpr int BUFSZ = 180 * PS;          // 12960 ushorts = 25920 B
    constexpr int NBUF = (NCH > 1) ? 2 : 1;

    __shared__ __align__(16) ushort s_in[NBUF * BUFSZ];

    constexpr int NWG = NT * NOCG * 8;
    int bid = blockIdx.x;
    bid = (bid & 7) * (NWG >> 3) + (bid >> 3);   // XCD-bijective swizzle

    int tile = bid % NT;
    int rest = bid / NT;
    int ocg = rest % NOCG;
    int b = rest / NOCG;
    int x0 = (tile % NTX) * 16;
    int y0 = (tile / NTX) * 8;

    int tid = threadIdx.x;
    int wv = tid >> 6;           // 0..7
    int lane = tid & 63;
    int n = lane & 15;
    int q = lane >> 4;
    int oc_half = (wv & 1) * 32;
    int sg = wv >> 1;            // site-group: rows sg*2, sg*2+1

    int ib[2];
#pragma unroll
    for (int f = 0; f < 2; ++f)
        ib[f] = ((sg * 2 + f) * 18 + n) * PS + q * 8;
    int iwa0 = q * 512 + (oc_half + n) * 8;
    int iwa1 = q * 512 + (oc_half + 16 + n) * 8;

    const ushort* inb = in + (size_t)b * HW * HW * 2 * CIN;

    f4v acc[2][2];
#pragma unroll
    for (int a = 0; a < 2; ++a)
#pragma unroll
        for (int f = 0; f < 2; ++f) acc[a][f] = (f4v){0.f, 0.f, 0.f, 0.f};

    // element i (0..2879): pos = i>>4, comp = (i>>3)&1, u = i&7
    auto elem_addr = [&](int i, int& ldsoff, const ushort*& gsrc) {
        int pos = i >> 4;
        int r2 = i & 15;
        int comp = r2 >> 3;
        int u = r2 & 7;
        int py = pos / 18, px = pos % 18;
        int gy = y0 - 1 + py, gx = x0 - 1 + px;
        ldsoff = pos * PS + comp * 32 + u * 4;
        gsrc = (gy >= 0 && gy < HW && gx >= 0 && gx < HW)
             ? inb + ((size_t)gy * HW + gx) * (2 * CIN) + comp * CIN + u * 4
             : nullptr;
    };

#define TAPS(T0, T1)                                                             \
    _Pragma("unroll")                                                            \
    for (int tap = T0; tap < T1; ++tap) {                                        \
        const int toff = ((tap / 3) * 18 + (tap % 3)) * PS;                      \
        const ushort* wt_ = wc + tap * 2048;                                     \
        h8v ah0 = *(const h8v*)(wt_ + iwa0);                                     \
        h8v ah1 = *(const h8v*)(wt_ + iwa1);                                     \
        h8v al0 = *(const h8v*)(wt_ + 18432 + iwa0);                             \
        h8v al1 = *(const h8v*)(wt_ + 18432 + iwa1);                             \
        h8v bh[2], bl[2];                                                        \
        _Pragma("unroll")                                                        \
        for (int f = 0; f < 2; ++f) {                                            \
            bh[f] = *(const h8v*)(&sb[toff + ib[f]]);                            \
            bl[f] = *(const h8v*)(&sb[toff + ib[f] + 32]);                       \
        }                                                                        \
        _Pragma("unroll")                                                        \
        for (int f = 0; f < 2; ++f) {                                            \
            acc[0][f] = __builtin_amdgcn_mfma_f32_16x16x32_f16(ah0, bh[f], acc[0][f], 0, 0, 0); \
            acc[1][f] = __builtin_amdgcn_mfma_f32_16x16x32_f16(ah1, bh[f], acc[1][f], 0, 0, 0); \
        }                                                                        \
        _Pragma("unroll")                                                        \
        for (int f = 0; f < 2; ++f) {                                            \
            acc[0][f] = __builtin_amdgcn_mfma_f32_16x16x32_f16(ah0, bl[f], acc[0][f], 0, 0, 0); \
            acc[1][f] = __builtin_amdgcn_mfma_f32_16x16x32_f16(ah1, bl[f], acc[1][f], 0, 0, 0); \
        }                                                                        \
        _Pragma("unroll")                                                        \
        for (int f = 0; f < 2; ++f) {                                            \
            acc[0][f] = __builtin_amdgcn_mfma_f32_16x16x32_f16(al0, bh[f], acc[0][f], 0, 0, 0); \
            acc[1][f] = __builtin_amdgcn_mfma_f32_16x16x32_f16(al1, bh[f], acc[1][f], 0, 0, 0); \
        }                                                                        \
    }

    if constexpr (NCH == 1) {
        // part1: pos < 144 (rows 0..7)
#pragma unroll
        for (int it = 0; it < 5; ++it) {
            int i = tid + it * 512;
            if (i < 2304) {
                int lo; const ushort* src;
                elem_addr(i, lo, src);
                uint2 v; v.x = 0u; v.y = 0u;
                if (src) v = *(const uint2*)src;
                *(uint2*)(&s_in[lo]) = v;
            }
        }
        // part2 (rows 8..9): issue loads to regs now, write after taps 0..2
        int lo0, lo1 = 0; const ushort* src0; const ushort* src1 = nullptr;
        elem_addr(2304 + tid, lo0, src0);
        bool has1 = tid < 64;
        if (has1) elem_addr(2816 + tid, lo1, src1);
        uint2 v0; v0.x = 0u; v0.y = 0u;
        uint2 v1; v1.x = 0u; v1.y = 0u;
        if (src0) v0 = *(const uint2*)src0;
        if (src1) v1 = *(const uint2*)src1;
        __syncthreads();

        const ushort* wc = wb + (size_t)(ocg * 2) * 18432;
        const ushort* sb = &s_in[0];
        __builtin_amdgcn_s_setprio(1);
        TAPS(0, 3)
        __builtin_amdgcn_s_setprio(0);
        *(uint2*)(&s_in[lo0]) = v0;
        if (has1) *(uint2*)(&s_in[lo1]) = v1;
        __syncthreads();
        __builtin_amdgcn_s_setprio(1);
        TAPS(3, 9)
        __builtin_amdgcn_s_setprio(0);
    } else {
        auto stage = [&](int ch, int bsel) {
#pragma unroll
            for (int it = 0; it < 6; ++it) {
                int i = tid + it * 512;
                if (i < 2880) {
                    int lo; const ushort* src;
                    elem_addr(i, lo, src);
                    uint2 v; v.x = 0u; v.y = 0u;
                    if (src) v = *(const uint2*)(src + (size_t)ch * 32);
                    *(uint2*)(&s_in[bsel * BUFSZ + lo]) = v;
                }
            }
        };

        stage(0, 0);
        int cur = 0;
        for (int ch = 0; ch < NCH; ++ch) {
            __syncthreads();                       // buf[cur] ready
            if (ch + 1 < NCH) stage(ch + 1, cur ^ 1);

            const ushort* wc = wb + (size_t)((ocg * NCH + ch) * 2) * 18432;
            const ushort* sb = &s_in[cur * BUFSZ];
            __builtin_amdgcn_s_setprio(1);
            TAPS(0, 9)
            __builtin_amdgcn_s_setprio(0);
            cur ^= 1;
        }
    }
#undef TAPS

    // epilogue: D row = oc (q*4+r), col = site (n); y-row = sg*2+f, x = n
    float vr[2][2][4];
#pragma unroll
    for (int tf = 0; tf < 2; ++tf)
#pragma unroll
        for (int f = 0; f < 2; ++f) {
            int y = y0 + sg * 2 + f;
#pragma unroll
            for (int r = 0; r < 4; ++r) {
                int oc = ocg * 64 + oc_half + tf * 16 + q * 4 + r;
                float v = fmaxf(acc[tf][f][r] * (g[oc] * BN_INV) + be[oc], 0.f);
                vr[tf][f][r] = v;
                out[((size_t)(b * COUT + oc) * HW + y) * HW + (x0 + n)] = v;
            }
        }

    if (POOL) {
#pragma unroll
        for (int tf = 0; tf < 2; ++tf) {
            ushort h[4], l[4];
#pragma unroll
            for (int r = 0; r < 4; ++r) {
                float p = fmaxf(vr[tf][0][r], vr[tf][1][r]);
                p = fmaxf(p, __shfl_xor(p, 1));
                fsplit(p, h[r], l[r]);
            }
            if ((n & 1) == 0) {
                int pyp = (y0 >> 1) + sg;
                int pxp = (x0 + n) >> 1;
                int ocb = ocg * 64 + oc_half + tf * 16 + q * 4;
                ushort* op = pooled
                    + (((size_t)b * (HW / 2) + pyp) * (HW / 2) + pxp) * (2 * COUT);
                uint2 uh, ul;
                uh.x = (uint)h[0] | ((uint)h[1] << 16);
                uh.y = (uint)h[2] | ((uint)h[3] << 16);
                ul.x = (uint)l[0] | ((uint)l[1] << 16);
                ul.y = (uint)l[2] | ((uint)l[3] << 16);
                *(uint2*)(op + ocb) = uh;
                *(uint2*)(op + COUT + ocb) = ul;
            }
        }
    }
}

// ---------------------------------------------------------------------------
// Quantum stage + BN + ReLU (fp32). Round-3-verified f2v packed version.
// ---------------------------------------------------------------------------
__global__ __launch_bounds__(256) void quantum_bn_relu(
    const float* __restrict__ e4,  // (8,256,32,32)
    const float* __restrict__ U,   // (256,16,16,2)
    const float* __restrict__ g5, const float* __restrict__ b5,
    float* __restrict__ out)       // (8,256,32,32)
{
    int blk = blockIdx.x;      // b*256 + c
    int c = blk & 255;
    __shared__ float sp[35][36];
    __shared__ __align__(16) float sU[512];

    int tid = threadIdx.x;
    for (int i = tid; i < 35 * 36; i += 256) ((float*)sp)[i] = 0.f;
    const float4* Usrc = (const float4*)(U + (size_t)c * 512);
    if (tid < 128) ((float4*)sU)[tid] = Usrc[tid];
    float4 pv = ((const float4*)(e4 + (size_t)blk * 1024))[tid];
    __syncthreads();
    {
        int y = tid >> 3, x4 = (tid & 7) << 2;
        sp[y + 1][x4 + 1] = pv.x;
        sp[y + 1][x4 + 2] = pv.y;
        sp[y + 1][x4 + 3] = pv.z;
        sp[y + 1][x4 + 4] = pv.w;
    }
    __syncthreads();

    int y = tid >> 3, x4 = (tid & 7) << 2;
    float rows[4][8];
#pragma unroll
    for (int i = 0; i < 4; ++i) {
        float4 a = *(const float4*)&sp[y + i][x4];
        float4 bq = *(const float4*)&sp[y + i][x4 + 4];
        rows[i][0] = a.x;  rows[i][1] = a.y;  rows[i][2] = a.z;  rows[i][3] = a.w;
        rows[i][4] = bq.x; rows[i][5] = bq.y; rows[i][6] = bq.z; rows[i][7] = bq.w;
    }

    float inv2[4];
#pragma unroll
    for (int k = 0; k < 4; ++k) {
        float ss = 0.f;
#pragma unroll
        for (int i = 0; i < 4; ++i)
#pragma unroll
            for (int j = 0; j < 4; ++j) {
                float v = rows[i][k + j];
                ss += v * v;
            }
        float inv = 1.f / fmaxf(sqrtf(ss), 1e-12f);
        inv2[k] = inv * inv;
    }

    const int   RI[10] = {0, 1, 2, 4, 7, 8, 11, 13, 14, 15};
    const float ZM[10] = {1.f, .5f, .5f, .5f, -.5f, .5f, -.5f, -.5f, -.5f, -1.f};
    const float4* sU4 = (const float4*)sU;

    float s[4] = {0.f, 0.f, 0.f, 0.f};
#pragma unroll
    for (int ii = 0; ii < 10; ++ii) {
        int i = RI[ii];
        f2v p0 = {0.f, 0.f}, p1 = {0.f, 0.f}, p2 = {0.f, 0.f}, p3 = {0.f, 0.f};
#pragma unroll
        for (int jj = 0; jj < 8; ++jj) {
            float4 u = sU4[i * 8 + jj];
            f2v u01 = {u.x, u.y};
            f2v u23 = {u.z, u.w};
            const int e0 = 2 * jj, e1 = 2 * jj + 1;
            p0 += u01 * rows[e0 >> 2][0 + (e0 & 3)];
            p1 += u01 * rows[e0 >> 2][1 + (e0 & 3)];
            p2 += u01 * rows[e0 >> 2][2 + (e0 & 3)];
            p3 += u01 * rows[e0 >> 2][3 + (e0 & 3)];
            p0 += u23 * rows[e1 >> 2][0 + (e1 & 3)];
            p1 += u23 * rows[e1 >> 2][1 + (e1 & 3)];
            p2 += u23 * rows[e1 >> 2][2 + (e1 & 3)];
            p3 += u23 * rows[e1 >> 2][3 + (e1 & 3)];
        }
        float zm = ZM[ii];
        s[0] += (p0.x * p0.x + p0.y * p0.y) * zm;
        s[1] += (p1.x * p1.x + p1.y * p1.y) * zm;
        s[2] += (p2.x * p2.x + p2.y * p2.y) * zm;
        s[3] += (p3.x * p3.x + p3.y * p3.y) * zm;
    }

    float sc = g5[c] * BN_INV, bi = b5[c];
    float4 o;
    o.x = fmaxf(((s[0] * inv2[0] + 1.f) * 0.5f) * sc + bi, 0.f);
    o.y = fmaxf(((s[1] * inv2[1] + 1.f) * 0.5f) * sc + bi, 0.f);
    o.z = fmaxf(((s[2] * inv2[2] + 1.f) * 0.5f) * sc + bi, 0.f);
    o.w = fmaxf(((s[3] * inv2[3] + 1.f) * 0.5f) * sc + bi, 0.f);
    *(float4*)(out + (size_t)blk * 1024 + y * 32 + x4) = o;
}

// ---------------------------------------------------------------------------
extern "C" void kernel_launch(void* const* d_in, const int* in_sizes, int n_in,
                              void* d_out, int out_size, void* d_ws, size_t ws_size,
                              hipStream_t stream)
{
    const float* x   = (const float*)d_in[0];
    const float* w1  = (const float*)d_in[1];
    const float* g1  = (const float*)d_in[2];
    const float* b1  = (const float*)d_in[3];
    const float* w2  = (const float*)d_in[4];
    const float* g2  = (const float*)d_in[5];
    const float* b2  = (const float*)d_in[6];
    const float* w3  = (const float*)d_in[7];
    const float* g3  = (const float*)d_in[8];
    const float* b3  = (const float*)d_in[9];
    const float* w4  = (const float*)d_in[10];
    const float* g4  = (const float*)d_in[11];
    const float* b4  = (const float*)d_in[12];
    const float* qw0 = (const float*)d_in[13];
    const float* qw1 = (const float*)d_in[14];
    const float* g5  = (const float*)d_in[15];
    const float* b5  = (const float*)d_in[16];

    float* out = (float*)d_out;
    float* e1  = out;                         // 8*32*256*256 = 16777216
    float* e2  = out + 16777216;              // 8*64*128*128 =  8388608
    float* e3  = out + 25165824;              // 8*128*64*64  =  4194304
    float* o4  = out + 29360128;              // 8*256*32*32  =  2097152

    float* ws = (float*)d_ws;
    float*  Uw  = ws;
    ushort* wb2 = (ushort*)(ws + 131072);
    ushort* wb3 = (ushort*)(ws + 149504);
    ushort* wb4 = (ushort*)(ws + 223232);
    ushort* pt1 = (ushort*)(ws + 518144);     // (8,128,128,64)
    ushort* pt2 = (ushort*)(ws + 4712448);    // (8,64,64,128)
    ushort* pt3 = (ushort*)(ws + 518144);     // (8,32,32,256), aliases pt1

    prep_conv1_kernel<<<2552, 256, 0, stream>>>(
        qw0, qw1, Uw, w2, wb2, w3, wb3, w4, wb4,
        x, w1, g1, b1, e1, pt1);

    conv3x3_mfma_split<32, 64, 128, true><<<1024, 512, 0, stream>>>(pt1, wb2, g2, b2, e2, pt2);

    conv3x3_mfma_split<64, 128, 64, true><<<512, 512, 0, stream>>>(pt2, wb3, g3, b3, e3, pt3);

    conv3x3_mfma_split<128, 256, 32, false><<<256, 512, 0, stream>>>(pt3, wb4, g4, b4, o4, nullptr);

    quantum_bn_relu<<<2048, 256, 0, stream>>>(o4, Uw, g5, b5, o4);
}